// Round 6
// baseline (164.329 us; speedup 1.0000x reference)
//
#include <hip/hip_runtime.h>
#include <hip/hip_cooperative_groups.h>
#include <math.h>

namespace cg = cooperative_groups;

#define B_ 2048
#define D_ 512
#define H_ 512
#define A_ 18
#define T_ 16
#define MT 48            // rows per gemm tile (3 m-tiles of 16)
#define GRIDX 256
#define MTF 16
#define MAXTILESF 144

typedef __attribute__((ext_vector_type(8))) short short8;
typedef __attribute__((ext_vector_type(4))) float f32x4;

// ws layout:
//   [0..16384)   ints: [0] ntiles | [17..34) offsets[T+1] | [50..130) tiles | [256..2304) order[B]
//   PART_OFF     float part[4][B][A]   (576 KB)
//   XSB_OFF      bf16 xs_b[B][D]       (2 MB)
//   W1T_OFF      bf16 w1t[T][H][D]     (8 MB)
#define PART_OFF 16384
#define XSB_OFF  (1 << 20)
#define W1T_OFF  (4 << 20)
#define WS_NEED  (12 << 20)

__device__ __forceinline__ unsigned short f2bf(float f) {
    union { float f; unsigned int u; } v; v.f = f;
    unsigned int u = v.u;
    return (unsigned short)((u + 0x7fffu + ((u >> 16) & 1u)) >> 16);
}

__global__ __launch_bounds__(256, 2) void nk_mega(
        const float* __restrict__ xs, const float* __restrict__ W1,
        const float* __restrict__ b1, const float* __restrict__ W2,
        const float* __restrict__ b2, const int* __restrict__ task_id,
        const int* __restrict__ action, float* __restrict__ out,
        int* __restrict__ wsi, unsigned short* __restrict__ xs_b,
        unsigned short* __restrict__ w1t, float* __restrict__ part) {
    cg::grid_group grid = cg::this_grid();
    __shared__ float smem[48 * 132];    // 25.3 KB, reused across phases
    __shared__ int s_int[MT];

    int bid = blockIdx.x, tid = threadIdx.x;

    // ======== Phase A: block 0 sorts; blocks 1..255 transpose W1 + convert xs ========
    if (bid == 0) {
        int* cnt = s_int; int* cur = s_int + T_; int* soff = s_int + 2 * T_;
        if (tid < T_) { cnt[tid] = 0; cur[tid] = 0; }
        __syncthreads();
        for (int b = tid; b < B_; b += 256) atomicAdd(&cnt[task_id[b]], 1);
        __syncthreads();
        if (tid == 0) {
            int off = 0, tot = 0;
            for (int t = 0; t < T_; ++t) {
                soff[t] = off; wsi[17 + t] = off;
                int nt = (cnt[t] + MT - 1) / MT;
                for (int k = 0; k < nt; ++k) wsi[50 + tot++] = (t << 16) | k;
                off += cnt[t];
            }
            wsi[17 + T_] = off;
            wsi[0] = tot;
        }
        __syncthreads();
        for (int b = tid; b < B_; b += 256) {
            int t = task_id[b];
            int pos = atomicAdd(&cur[t], 1);
            wsi[256 + soff[t] + pos] = b;
        }
    } else {
        for (int u = bid - 1; u < 1536; u += (GRIDX - 1)) {
            if (u < 1024) {
                float (*tile)[65] = (float(*)[65])smem;
                int hx = u & 7, dy = (u >> 3) & 7, t = u >> 6;
                int cx = tid & 63, ry = tid >> 6;
                const float* src = W1 + ((size_t)t * D_ + dy * 64) * H_ + hx * 64;
#pragma unroll
                for (int i = 0; i < 16; ++i) {
                    int row = i * 4 + ry;
                    tile[row][cx] = src[(size_t)row * H_ + cx];
                }
                __syncthreads();
                unsigned short* dst = w1t + ((size_t)t * H_ + hx * 64) * D_ + dy * 64;
                int c4 = tid & 15, hr0 = tid >> 4;
#pragma unroll
                for (int i = 0; i < 4; ++i) {
                    int hr = hr0 + i * 16;
                    unsigned short uu[4] = { f2bf(tile[c4 * 4 + 0][hr]), f2bf(tile[c4 * 4 + 1][hr]),
                                             f2bf(tile[c4 * 4 + 2][hr]), f2bf(tile[c4 * 4 + 3][hr]) };
                    *(uint2*)(dst + (size_t)hr * D_ + c4 * 4) = *(const uint2*)uu;
                }
                __syncthreads();
            } else {
                size_t off = ((size_t)(u - 1024) * 256 + tid) * 8;
                float4 x0 = *(const float4*)(xs + off);
                float4 x1 = *(const float4*)(xs + off + 4);
                unsigned short uu[8] = { f2bf(x0.x), f2bf(x0.y), f2bf(x0.z), f2bf(x0.w),
                                         f2bf(x1.x), f2bf(x1.y), f2bf(x1.z), f2bf(x1.w) };
                *(uint4*)(xs_b + off) = *(const uint4*)uu;
            }
        }
    }
    __threadfence();
    grid.sync();

    // ======== Phase B: gemm (48 rows x 128 cols per unit) + relu + partial fc2 ========
    {
        float (*h_lds)[132] = (float(*)[132])smem;
        int ntiles = wsi[0];
        for (int u = bid; u < ntiles * 4; u += GRIDX) {
            int ti = u >> 2, cq = u & 3;
            int code = wsi[50 + ti];
            int t = code >> 16, kt = code & 0xffff;
            int off0 = wsi[17 + t], off1 = wsi[17 + t + 1];
            int rowbase = off0 + kt * MT;
            int rows = off1 - rowbase; if (rows > MT) rows = MT;
            int lane = tid & 63, w = tid >> 6, r15 = lane & 15, kg = lane >> 4;

            if (tid < MT) s_int[tid] = wsi[256 + rowbase + (tid < rows ? tid : rows - 1)];
            __syncthreads();

            const unsigned short* ap0 = xs_b + (size_t)s_int[r15] * D_ + kg * 8;
            const unsigned short* ap1 = xs_b + (size_t)s_int[16 + r15] * D_ + kg * 8;
            const unsigned short* ap2 = xs_b + (size_t)s_int[32 + r15] * D_ + kg * 8;
            int col0 = cq * 128 + w * 32;
            const unsigned short* bp0 = w1t + (size_t)t * H_ * D_ + (size_t)(col0 + r15) * D_ + kg * 8;
            const unsigned short* bp1 = bp0 + (size_t)16 * D_;

            f32x4 acc00 = {0.f,0.f,0.f,0.f}, acc01 = {0.f,0.f,0.f,0.f};
            f32x4 acc10 = {0.f,0.f,0.f,0.f}, acc11 = {0.f,0.f,0.f,0.f};
            f32x4 acc20 = {0.f,0.f,0.f,0.f}, acc21 = {0.f,0.f,0.f,0.f};
#pragma unroll
            for (int ks = 0; ks < 16; ++ks) {
                short8 a0 = *(const short8*)(ap0 + ks * 32);
                short8 a1 = *(const short8*)(ap1 + ks * 32);
                short8 a2 = *(const short8*)(ap2 + ks * 32);
                short8 bf0 = *(const short8*)(bp0 + ks * 32);
                short8 bf1 = *(const short8*)(bp1 + ks * 32);
                acc00 = __builtin_amdgcn_mfma_f32_16x16x32_bf16(a0, bf0, acc00, 0, 0, 0);
                acc01 = __builtin_amdgcn_mfma_f32_16x16x32_bf16(a0, bf1, acc01, 0, 0, 0);
                acc10 = __builtin_amdgcn_mfma_f32_16x16x32_bf16(a1, bf0, acc10, 0, 0, 0);
                acc11 = __builtin_amdgcn_mfma_f32_16x16x32_bf16(a1, bf1, acc11, 0, 0, 0);
                acc20 = __builtin_amdgcn_mfma_f32_16x16x32_bf16(a2, bf0, acc20, 0, 0, 0);
                acc21 = __builtin_amdgcn_mfma_f32_16x16x32_bf16(a2, bf1, acc21, 0, 0, 0);
            }

            float bv0 = b1[t * H_ + col0 + r15];
            float bv1 = b1[t * H_ + col0 + 16 + r15];
#pragma unroll
            for (int j = 0; j < 4; ++j) {
                int rr = kg * 4 + j;
                float v;
                v = acc00[j] + bv0; h_lds[rr][w * 32 + r15]           = v > 0.f ? v : 0.f;
                v = acc01[j] + bv1; h_lds[rr][w * 32 + 16 + r15]      = v > 0.f ? v : 0.f;
                v = acc10[j] + bv0; h_lds[16 + rr][w * 32 + r15]      = v > 0.f ? v : 0.f;
                v = acc11[j] + bv1; h_lds[16 + rr][w * 32 + 16 + r15] = v > 0.f ? v : 0.f;
                v = acc20[j] + bv0; h_lds[32 + rr][w * 32 + r15]      = v > 0.f ? v : 0.f;
                v = acc21[j] + bv1; h_lds[32 + rr][w * 32 + 16 + r15] = v > 0.f ? v : 0.f;
            }
            __syncthreads();

            // partial fc2 over this unit's 128 h-cols: 16 lanes/row, 3 row-groups
            int gb = tid >> 4, l16 = tid & 15;
            const float* wr = W2 + ((size_t)t * H_ + cq * 128 + l16 * 8) * A_;
#pragma unroll
            for (int gg = 0; gg < 3; ++gg) {
                int g = gb + gg * 16;
                float lg[A_];
#pragma unroll
                for (int a = 0; a < A_; ++a) lg[a] = 0.f;
                float4 hv0 = *(const float4*)&h_lds[g][l16 * 8];
                float4 hv1 = *(const float4*)&h_lds[g][l16 * 8 + 4];
#pragma unroll
                for (int a = 0; a < A_; ++a) {
                    float s = fmaf(hv0.x, wr[a], lg[a]);
                    s = fmaf(hv0.y, wr[A_ + a], s);
                    s = fmaf(hv0.z, wr[2 * A_ + a], s);
                    s = fmaf(hv0.w, wr[3 * A_ + a], s);
                    s = fmaf(hv1.x, wr[4 * A_ + a], s);
                    s = fmaf(hv1.y, wr[5 * A_ + a], s);
                    s = fmaf(hv1.z, wr[6 * A_ + a], s);
                    lg[a] = fmaf(hv1.w, wr[7 * A_ + a], s);
                }
#pragma unroll
                for (int a = 0; a < A_; ++a) {
                    lg[a] += __shfl_down(lg[a], 8, 16);
                    lg[a] += __shfl_down(lg[a], 4, 16);
                    lg[a] += __shfl_down(lg[a], 2, 16);
                    lg[a] += __shfl_down(lg[a], 1, 16);
                }
                if (l16 == 0 && g < rows) {
                    float* pp = part + ((size_t)cq * B_ + rowbase + g) * A_;
#pragma unroll
                    for (int a = 0; a < A_; ++a) pp[a] = lg[a];
                }
            }
            __syncthreads();
        }
    }
    __threadfence();
    grid.sync();

    // ======== Phase C: sum partials + softmax + write outputs (8 rows/block) ========
    if (tid < 8) {
        int r = bid * 8 + tid;
        if (r < B_) {
            int t = 0;
#pragma unroll
            for (int i = 1; i < T_; ++i) t += (r >= wsi[17 + i]) ? 1 : 0;
            int b = wsi[256 + r];
            const float* p0 = part + (size_t)r * A_;
            float logits[A_];
            float m = -1e30f;
#pragma unroll
            for (int a = 0; a < A_; ++a) {
                float v = p0[a] + p0[(size_t)B_ * A_ + a] + p0[2 * (size_t)B_ * A_ + a]
                        + p0[3 * (size_t)B_ * A_ + a] + b2[t * A_ + a];
                logits[a] = v;
                m = fmaxf(m, v);
            }
            float S = 0.f, sle = 0.f;
#pragma unroll
            for (int a = 0; a < A_; ++a) {
                float e = expf(logits[a] - m);
                S += e;
                sle += logits[a] * e;
            }
            float logZ = m + logf(S);
            int as = action[b];
            out[b] = (float)as;
            out[B_ + b] = logits[as] - logZ;
            out[2 * B_ + b] = logZ - sle / S;
        }
    }
}

// ---------------- fallback path (round-1, known-good) ----------------

__global__ void nk_init(int* wsi) { int i = threadIdx.x; if (i < 50) wsi[i] = 0; }

__global__ void nk_count(const int* task_id, int* wsi) {
    int b = blockIdx.x * blockDim.x + threadIdx.x;
    if (b < B_) atomicAdd(&wsi[1 + task_id[b]], 1);
}

__global__ void nk_plan(int* wsi) {
    int off = 0, tot = 0;
    for (int t = 0; t < T_; ++t) {
        wsi[17 + t] = off;
        int cnt = wsi[1 + t];
        int nt = (cnt + MTF - 1) / MTF;
        for (int k = 0; k < nt; ++k) wsi[50 + tot++] = (t << 16) | k;
        off += cnt;
    }
    wsi[17 + T_] = off;
    wsi[0] = tot;
}

__global__ void nk_scatter(const int* task_id, int* wsi) {
    int b = blockIdx.x * blockDim.x + threadIdx.x;
    if (b < B_) {
        int t = task_id[b];
        int pos = atomicAdd(&wsi[34 + t], 1);
        wsi[256 + wsi[17 + t] + pos] = b;
    }
}

__global__ __launch_bounds__(512) void nk_main(
        const float* __restrict__ xs, const float* __restrict__ W1,
        const float* __restrict__ b1, const float* __restrict__ W2,
        const float* __restrict__ b2, const int* __restrict__ task_id,
        const int* __restrict__ action, float* __restrict__ out,
        const int* __restrict__ wsi) {
    __shared__ float tile[MTF][D_];
    __shared__ int sidx[MTF];
    int bid = blockIdx.x;
    if (bid >= wsi[0]) return;
    int code = wsi[50 + bid];
    int t = code >> 16, kt = code & 0xffff;
    int off0 = wsi[17 + t], off1 = wsi[17 + t + 1];
    int base = off0 + kt * MTF;
    int rows = off1 - base; if (rows > MTF) rows = MTF;
    int tid = threadIdx.x;
    if (tid < MTF) sidx[tid] = (tid < rows) ? wsi[256 + base + tid] : -1;
    __syncthreads();
    for (int i = 0; i < MTF; ++i) {
        int b = sidx[i];
        tile[i][tid] = (b >= 0) ? xs[(size_t)b * D_ + tid] : 0.f;
    }
    __syncthreads();
    const float* w1p = W1 + (size_t)t * D_ * H_ + tid;
    float acc[MTF];
#pragma unroll
    for (int i = 0; i < MTF; ++i) acc[i] = 0.f;
    for (int d = 0; d < D_; d += 4) {
        float w0 = w1p[(size_t)(d + 0) * H_];
        float w1v = w1p[(size_t)(d + 1) * H_];
        float w2v = w1p[(size_t)(d + 2) * H_];
        float w3v = w1p[(size_t)(d + 3) * H_];
#pragma unroll
        for (int i = 0; i < MTF; ++i) {
            float4 x = *(const float4*)&tile[i][d];
            float a0 = fmaf(x.x, w0, acc[i]);
            a0 = fmaf(x.y, w1v, a0);
            a0 = fmaf(x.z, w2v, a0);
            acc[i] = fmaf(x.w, w3v, a0);
        }
    }
    __syncthreads();
    float b1v = b1[t * H_ + tid];
#pragma unroll
    for (int i = 0; i < MTF; ++i) {
        float h = acc[i] + b1v;
        tile[i][tid] = h > 0.f ? h : 0.f;
    }
    __syncthreads();
    int g = tid >> 5, l = tid & 31;
    float lg[A_];
#pragma unroll
    for (int a = 0; a < A_; ++a) lg[a] = 0.f;
    const float* w2base = W2 + (size_t)t * H_ * A_;
    for (int hh = l; hh < H_; hh += 32) {
        float hv = tile[g][hh];
        const float* wrow = w2base + (size_t)hh * A_;
#pragma unroll
        for (int a = 0; a < A_; ++a) lg[a] = fmaf(hv, wrow[a], lg[a]);
    }
#pragma unroll
    for (int a = 0; a < A_; ++a) {
        lg[a] += __shfl_down(lg[a], 16, 32);
        lg[a] += __shfl_down(lg[a], 8, 32);
        lg[a] += __shfl_down(lg[a], 4, 32);
        lg[a] += __shfl_down(lg[a], 2, 32);
        lg[a] += __shfl_down(lg[a], 1, 32);
    }
    if (l == 0 && g < rows) {
        int b = sidx[g];
        float logits[A_];
        float m = -1e30f;
#pragma unroll
        for (int a = 0; a < A_; ++a) {
            logits[a] = lg[a] + b2[t * A_ + a];
            m = fmaxf(m, logits[a]);
        }
        float S = 0.f, sle = 0.f;
#pragma unroll
        for (int a = 0; a < A_; ++a) {
            float e = expf(logits[a] - m);
            S += e;
            sle += logits[a] * e;
        }
        float logZ = m + logf(S);
        int as = action[b];
        out[b] = (float)as;
        out[B_ + b] = logits[as] - logZ;
        out[2 * B_ + b] = logZ - sle / S;
    }
}

extern "C" void kernel_launch(void* const* d_in, const int* in_sizes, int n_in,
                              void* d_out, int out_size, void* d_ws, size_t ws_size,
                              hipStream_t stream) {
    const float* xs = (const float*)d_in[0];
    const float* W1 = (const float*)d_in[1];
    const float* b1 = (const float*)d_in[2];
    const float* W2 = (const float*)d_in[3];
    const float* b2 = (const float*)d_in[4];
    const int* task_id = (const int*)d_in[5];
    const int* action = (const int*)d_in[6];
    float* out = (float*)d_out;

    if (ws_size >= WS_NEED) {
        unsigned char* wsb = (unsigned char*)d_ws;
        int* wsi = (int*)d_ws;
        float* part = (float*)(wsb + PART_OFF);
        unsigned short* xs_b = (unsigned short*)(wsb + XSB_OFF);
        unsigned short* w1t = (unsigned short*)(wsb + W1T_OFF);

        void* args[] = { (void*)&xs, (void*)&W1, (void*)&b1, (void*)&W2, (void*)&b2,
                         (void*)&task_id, (void*)&action, (void*)&out,
                         (void*)&wsi, (void*)&xs_b, (void*)&w1t, (void*)&part };
        hipLaunchCooperativeKernel((const void*)nk_mega, dim3(GRIDX), dim3(256),
                                   args, 0, stream);
    } else {
        int* wsi = (int*)d_ws;
        nk_init<<<1, 64, 0, stream>>>(wsi);
        nk_count<<<(B_ + 255) / 256, 256, 0, stream>>>(task_id, wsi);
        nk_plan<<<1, 1, 0, stream>>>(wsi);
        nk_scatter<<<(B_ + 255) / 256, 256, 0, stream>>>(task_id, wsi);
        nk_main<<<MAXTILESF, 512, 0, stream>>>(xs, W1, b1, W2, b2, task_id, action, out, wsi);
    }
}

// Round 7
// 35.665 us; speedup vs baseline: 4.6076x; 4.6076x over previous
//
#include <hip/hip_runtime.h>
#include <math.h>

#define B_ 2048
#define D_ 512
#define H_ 512
#define A_ 18
#define T_ 16
#define MTF 16
#define MAXTILESF 144

typedef __attribute__((ext_vector_type(8))) short short8;
typedef __attribute__((ext_vector_type(4))) float f32x4;

// ws layout:
//   [0..16384)    ints: [17..34) offsets[T+1] | [256..2304) order[B]   (fallback uses more)
//   XSB_OFF 1MB   bf16 xs_b[B][D]        (2 MB)
//   W2T_OFF 3MB   bf16 w2t[T][32][512]   (512 KB, a=18..31 zeroed)
//   W1T_OFF 4MB   bf16 w1t[T][H][D]      (8 MB)
#define XSB_OFF  (1 << 20)
#define W2T_OFF  (3 << 20)
#define W1T_OFF  (4 << 20)
#define WS_NEED  (12 << 20)

__device__ __forceinline__ unsigned short f2bf(float f) {
    union { float f; unsigned int u; } v; v.f = f;
    unsigned int u = v.u;
    return (unsigned short)((u + 0x7fffu + ((u >> 16) & 1u)) >> 16);
}

// ---- prep: [0,1024) W1 transpose; [1024,1536) xs->bf16; [1536,1552) W2T; 1552 sort ----
__global__ __launch_bounds__(256) void nk_prep(const float* __restrict__ W1,
                                               const float* __restrict__ xs,
                                               const float* __restrict__ W2,
                                               const int* __restrict__ task_id,
                                               unsigned short* __restrict__ w1t,
                                               unsigned short* __restrict__ xs_b,
                                               unsigned short* __restrict__ w2t,
                                               int* __restrict__ wsi) {
    int bid = blockIdx.x;
    int tid = threadIdx.x;
    if (bid < 1024) {
        __shared__ float tile[64][65];
        int hx = bid & 7, dy = (bid >> 3) & 7, t = bid >> 6;
        int cx = tid & 63, ry = tid >> 6;
        const float* src = W1 + ((size_t)t * D_ + dy * 64) * H_ + hx * 64;
#pragma unroll
        for (int i = 0; i < 16; ++i) {
            int row = i * 4 + ry;
            tile[row][cx] = src[(size_t)row * H_ + cx];
        }
        __syncthreads();
        unsigned short* dst = w1t + ((size_t)t * H_ + hx * 64) * D_ + dy * 64;
        int c4 = tid & 15, hr0 = tid >> 4;
#pragma unroll
        for (int i = 0; i < 4; ++i) {
            int hr = hr0 + i * 16;
            unsigned short uu[4] = { f2bf(tile[c4 * 4 + 0][hr]), f2bf(tile[c4 * 4 + 1][hr]),
                                     f2bf(tile[c4 * 4 + 2][hr]), f2bf(tile[c4 * 4 + 3][hr]) };
            *(uint2*)(dst + (size_t)hr * D_ + c4 * 4) = *(const uint2*)uu;
        }
    } else if (bid < 1536) {
        size_t off = ((size_t)(bid - 1024) * 256 + tid) * 8;
        float4 x0 = *(const float4*)(xs + off);
        float4 x1 = *(const float4*)(xs + off + 4);
        unsigned short uu[8] = { f2bf(x0.x), f2bf(x0.y), f2bf(x0.z), f2bf(x0.w),
                                 f2bf(x1.x), f2bf(x1.y), f2bf(x1.z), f2bf(x1.w) };
        *(uint4*)(xs_b + off) = *(const uint4*)uu;
    } else if (bid < 1552) {
        // W2 [t][512][18] fp32 -> w2t [t][32][512] bf16 (a>=18 zero)
        int t = bid - 1536;
        const float* src = W2 + (size_t)t * H_ * A_;
        unsigned short* dst = w2t + (size_t)t * 32 * H_;
#pragma unroll
        for (int i = 0; i < 2; ++i) {
            int h = tid * 2 + i;
            float v[A_];
#pragma unroll
            for (int a = 0; a < A_; ++a) v[a] = src[(size_t)h * A_ + a];
#pragma unroll
            for (int a = 0; a < A_; ++a) dst[(size_t)a * H_ + h] = f2bf(v[a]);
#pragma unroll
            for (int a = A_; a < 32; ++a) dst[(size_t)a * H_ + h] = 0;
        }
    } else {
        __shared__ int cnt[T_], cur[T_], soff[T_];
        if (tid < T_) { cnt[tid] = 0; cur[tid] = 0; }
        __syncthreads();
        for (int b = tid; b < B_; b += 256) atomicAdd(&cnt[task_id[b]], 1);
        __syncthreads();
        if (tid == 0) {
            int off = 0;
            for (int t = 0; t < T_; ++t) {
                soff[t] = off; wsi[17 + t] = off;
                off += cnt[t];
            }
            wsi[17 + T_] = off;
        }
        __syncthreads();
        for (int b = tid; b < B_; b += 256) {
            int t = task_id[b];
            int pos = atomicAdd(&cur[t], 1);
            wsi[256 + soff[t] + pos] = b;
        }
    }
}

// ---- fused: fc1 MFMA (16 rows x 512 cols / block) + relu + fc2 MFMA + softmax ----
__global__ __launch_bounds__(512) void nk_fused(
        const unsigned short* __restrict__ xs_b,
        const unsigned short* __restrict__ w1t,
        const unsigned short* __restrict__ w2t,
        const float* __restrict__ b1, const float* __restrict__ b2,
        const int* __restrict__ action, float* __restrict__ out,
        const int* __restrict__ wsi) {
    __shared__ unsigned short h_lds[16][520];   // bf16, stride 1040B: 16B aligned, bank-friendly
    __shared__ float lg_lds[16][34];
    __shared__ int sidx[16];

    int t = blockIdx.x, kt = blockIdx.y;
    int off0 = wsi[17 + t], off1 = wsi[18 + t];
    int rowbase = off0 + kt * 16;
    int rows = off1 - rowbase;
    if (rows <= 0) return;
    if (rows > 16) rows = 16;

    int tid = threadIdx.x, lane = tid & 63, w = tid >> 6;
    int r15 = lane & 15, kg = lane >> 4;

    if (tid < 16) sidx[tid] = wsi[256 + rowbase + (tid < rows ? tid : rows - 1)];
    __syncthreads();

    // ---- fc1: wave w covers cols w*64 .. w*64+63 (4 n-tiles), rows 0..15
    const unsigned short* ap = xs_b + (size_t)sidx[r15] * D_ + kg * 8;
    const unsigned short* bbase = w1t + (size_t)t * H_ * D_ + kg * 8;
    const unsigned short* bp0 = bbase + (size_t)(w * 64 + r15) * D_;
    const unsigned short* bp1 = bp0 + (size_t)16 * D_;
    const unsigned short* bp2 = bp0 + (size_t)32 * D_;
    const unsigned short* bp3 = bp0 + (size_t)48 * D_;

    f32x4 acc0 = {0.f,0.f,0.f,0.f}, acc1 = {0.f,0.f,0.f,0.f};
    f32x4 acc2 = {0.f,0.f,0.f,0.f}, acc3 = {0.f,0.f,0.f,0.f};
#pragma unroll
    for (int ks = 0; ks < 16; ++ks) {
        short8 af = *(const short8*)(ap + ks * 32);
        short8 b0 = *(const short8*)(bp0 + ks * 32);
        short8 b1f = *(const short8*)(bp1 + ks * 32);
        short8 b2f = *(const short8*)(bp2 + ks * 32);
        short8 b3f = *(const short8*)(bp3 + ks * 32);
        acc0 = __builtin_amdgcn_mfma_f32_16x16x32_bf16(af, b0, acc0, 0, 0, 0);
        acc1 = __builtin_amdgcn_mfma_f32_16x16x32_bf16(af, b1f, acc1, 0, 0, 0);
        acc2 = __builtin_amdgcn_mfma_f32_16x16x32_bf16(af, b2f, acc2, 0, 0, 0);
        acc3 = __builtin_amdgcn_mfma_f32_16x16x32_bf16(af, b3f, acc3, 0, 0, 0);
    }

    // bias + relu -> h_lds bf16
    int colb = w * 64 + r15;
    float bv0 = b1[t * H_ + colb];
    float bv1 = b1[t * H_ + colb + 16];
    float bv2 = b1[t * H_ + colb + 32];
    float bv3 = b1[t * H_ + colb + 48];
#pragma unroll
    for (int j = 0; j < 4; ++j) {
        int row = kg * 4 + j;
        float v;
        v = acc0[j] + bv0; h_lds[row][colb]      = f2bf(v > 0.f ? v : 0.f);
        v = acc1[j] + bv1; h_lds[row][colb + 16] = f2bf(v > 0.f ? v : 0.f);
        v = acc2[j] + bv2; h_lds[row][colb + 32] = f2bf(v > 0.f ? v : 0.f);
        v = acc3[j] + bv3; h_lds[row][colb + 48] = f2bf(v > 0.f ? v : 0.f);
    }
    __syncthreads();

    // ---- fc2: wave 0 only; logits 16x32 (a<18 valid) via MFMA, K=512
    if (w == 0) {
        const unsigned short* wa0 = w2t + (size_t)t * 32 * H_ + (size_t)r15 * H_ + kg * 8;
        const unsigned short* wa1 = wa0 + (size_t)16 * H_;
        f32x4 c0 = {0.f,0.f,0.f,0.f}, c1 = {0.f,0.f,0.f,0.f};
#pragma unroll
        for (int ks = 0; ks < 16; ++ks) {
            short8 hf = *(const short8*)&h_lds[r15][ks * 32 + kg * 8];
            short8 w0 = *(const short8*)(wa0 + ks * 32);
            short8 w1f = *(const short8*)(wa1 + ks * 32);
            c0 = __builtin_amdgcn_mfma_f32_16x16x32_bf16(hf, w0, c0, 0, 0, 0);
            c1 = __builtin_amdgcn_mfma_f32_16x16x32_bf16(hf, w1f, c1, 0, 0, 0);
        }
        float bb0 = (r15 < A_) ? b2[t * A_ + r15] : 0.f;
        float bb1 = (16 + r15 < A_) ? b2[t * A_ + 16 + r15] : 0.f;
#pragma unroll
        for (int j = 0; j < 4; ++j) {
            int row = kg * 4 + j;
            lg_lds[row][r15] = c0[j] + bb0;
            lg_lds[row][16 + r15] = c1[j] + bb1;
        }
    }
    __syncthreads();

    // ---- softmax + outputs: one thread per row
    if (tid < rows) {
        int b = sidx[tid];
        float logits[A_];
        float m = -1e30f;
#pragma unroll
        for (int a = 0; a < A_; ++a) {
            logits[a] = lg_lds[tid][a];
            m = fmaxf(m, logits[a]);
        }
        float S = 0.f, sle = 0.f;
#pragma unroll
        for (int a = 0; a < A_; ++a) {
            float e = expf(logits[a] - m);
            S += e;
            sle += logits[a] * e;
        }
        float logZ = m + logf(S);
        int as = action[b];
        out[b] = (float)as;
        out[B_ + b] = logits[as] - logZ;
        out[2 * B_ + b] = logZ - sle / S;
    }
}

// ---------------- fallback path (round-1, known-good) ----------------

__global__ void nk_init(int* wsi) { int i = threadIdx.x; if (i < 50) wsi[i] = 0; }

__global__ void nk_count(const int* task_id, int* wsi) {
    int b = blockIdx.x * blockDim.x + threadIdx.x;
    if (b < B_) atomicAdd(&wsi[1 + task_id[b]], 1);
}

__global__ void nk_plan(int* wsi) {
    int off = 0, tot = 0;
    for (int t = 0; t < T_; ++t) {
        wsi[17 + t] = off;
        int cnt = wsi[1 + t];
        int nt = (cnt + MTF - 1) / MTF;
        for (int k = 0; k < nt; ++k) wsi[50 + tot++] = (t << 16) | k;
        off += cnt;
    }
    wsi[17 + T_] = off;
    wsi[0] = tot;
}

__global__ void nk_scatter(const int* task_id, int* wsi) {
    int b = blockIdx.x * blockDim.x + threadIdx.x;
    if (b < B_) {
        int t = task_id[b];
        int pos = atomicAdd(&wsi[34 + t], 1);
        wsi[256 + wsi[17 + t] + pos] = b;
    }
}

__global__ __launch_bounds__(512) void nk_main(
        const float* __restrict__ xs, const float* __restrict__ W1,
        const float* __restrict__ b1, const float* __restrict__ W2,
        const float* __restrict__ b2, const int* __restrict__ task_id,
        const int* __restrict__ action, float* __restrict__ out,
        const int* __restrict__ wsi) {
    __shared__ float tile[MTF][D_];
    __shared__ int sidx[MTF];
    int bid = blockIdx.x;
    if (bid >= wsi[0]) return;
    int code = wsi[50 + bid];
    int t = code >> 16, kt = code & 0xffff;
    int off0 = wsi[17 + t], off1 = wsi[17 + t + 1];
    int base = off0 + kt * MTF;
    int rows = off1 - base; if (rows > MTF) rows = MTF;
    int tid = threadIdx.x;
    if (tid < MTF) sidx[tid] = (tid < rows) ? wsi[256 + base + tid] : -1;
    __syncthreads();
    for (int i = 0; i < MTF; ++i) {
        int b = sidx[i];
        tile[i][tid] = (b >= 0) ? xs[(size_t)b * D_ + tid] : 0.f;
    }
    __syncthreads();
    const float* w1p = W1 + (size_t)t * D_ * H_ + tid;
    float acc[MTF];
#pragma unroll
    for (int i = 0; i < MTF; ++i) acc[i] = 0.f;
    for (int d = 0; d < D_; d += 4) {
        float w0 = w1p[(size_t)(d + 0) * H_];
        float w1v = w1p[(size_t)(d + 1) * H_];
        float w2v = w1p[(size_t)(d + 2) * H_];
        float w3v = w1p[(size_t)(d + 3) * H_];
#pragma unroll
        for (int i = 0; i < MTF; ++i) {
            float4 x = *(const float4*)&tile[i][d];
            float a0 = fmaf(x.x, w0, acc[i]);
            a0 = fmaf(x.y, w1v, a0);
            a0 = fmaf(x.z, w2v, a0);
            acc[i] = fmaf(x.w, w3v, a0);
        }
    }
    __syncthreads();
    float b1v = b1[t * H_ + tid];
#pragma unroll
    for (int i = 0; i < MTF; ++i) {
        float h = acc[i] + b1v;
        tile[i][tid] = h > 0.f ? h : 0.f;
    }
    __syncthreads();
    int g = tid >> 5, l = tid & 31;
    float lg[A_];
#pragma unroll
    for (int a = 0; a < A_; ++a) lg[a] = 0.f;
    const float* w2base = W2 + (size_t)t * H_ * A_;
    for (int hh = l; hh < H_; hh += 32) {
        float hv = tile[g][hh];
        const float* wrow = w2base + (size_t)hh * A_;
#pragma unroll
        for (int a = 0; a < A_; ++a) lg[a] = fmaf(hv, wrow[a], lg[a]);
    }
#pragma unroll
    for (int a = 0; a < A_; ++a) {
        lg[a] += __shfl_down(lg[a], 16, 32);
        lg[a] += __shfl_down(lg[a], 8, 32);
        lg[a] += __shfl_down(lg[a], 4, 32);
        lg[a] += __shfl_down(lg[a], 2, 32);
        lg[a] += __shfl_down(lg[a], 1, 32);
    }
    if (l == 0 && g < rows) {
        int b = sidx[g];
        float logits[A_];
        float m = -1e30f;
#pragma unroll
        for (int a = 0; a < A_; ++a) {
            logits[a] = lg[a] + b2[t * A_ + a];
            m = fmaxf(m, logits[a]);
        }
        float S = 0.f, sle = 0.f;
#pragma unroll
        for (int a = 0; a < A_; ++a) {
            float e = expf(logits[a] - m);
            S += e;
            sle += logits[a] * e;
        }
        float logZ = m + logf(S);
        int as = action[b];
        out[b] = (float)as;
        out[B_ + b] = logits[as] - logZ;
        out[2 * B_ + b] = logZ - sle / S;
    }
}

extern "C" void kernel_launch(void* const* d_in, const int* in_sizes, int n_in,
                              void* d_out, int out_size, void* d_ws, size_t ws_size,
                              hipStream_t stream) {
    const float* xs = (const float*)d_in[0];
    const float* W1 = (const float*)d_in[1];
    const float* b1 = (const float*)d_in[2];
    const float* W2 = (const float*)d_in[3];
    const float* b2 = (const float*)d_in[4];
    const int* task_id = (const int*)d_in[5];
    const int* action = (const int*)d_in[6];
    float* out = (float*)d_out;

    if (ws_size >= WS_NEED) {
        unsigned char* wsb = (unsigned char*)d_ws;
        int* wsi = (int*)d_ws;
        unsigned short* xs_b = (unsigned short*)(wsb + XSB_OFF);
        unsigned short* w2t = (unsigned short*)(wsb + W2T_OFF);
        unsigned short* w1t = (unsigned short*)(wsb + W1T_OFF);

        nk_prep<<<1553, 256, 0, stream>>>(W1, xs, W2, task_id, w1t, xs_b, w2t, wsi);
        nk_fused<<<dim3(T_, 128), 512, 0, stream>>>(xs_b, w1t, w2t, b1, b2,
                                                    action, out, wsi);
    } else {
        int* wsi = (int*)d_ws;
        nk_init<<<1, 64, 0, stream>>>(wsi);
        nk_count<<<(B_ + 255) / 256, 256, 0, stream>>>(task_id, wsi);
        nk_plan<<<1, 1, 0, stream>>>(wsi);
        nk_scatter<<<(B_ + 255) / 256, 256, 0, stream>>>(task_id, wsi);
        nk_main<<<MAXTILESF, 512, 0, stream>>>(xs, W1, b1, W2, b2, task_id, action, out, wsi);
    }
}

// Round 8
// 31.396 us; speedup vs baseline: 5.2340x; 1.1360x over previous
//
#include <hip/hip_runtime.h>
#include <math.h>

#define B_ 2048
#define D_ 512
#define H_ 512
#define A_ 18
#define T_ 16
#define MTF 16
#define MAXTILESF 144
#define NSLOT 24

typedef __attribute__((ext_vector_type(8))) short short8;
typedef __attribute__((ext_vector_type(4))) float f32x4;

// ws layout:
//   [0..16384)    ints: [17..34) offsets[T+1] | [256..2304) order[B]  (fallback uses more)
//   W2T_OFF 3MB   bf16 w2t[T][32][512]   (512 KB, a=18..31 zeroed)
//   W1T_OFF 4MB   bf16 w1t[T][H][D]      (8 MB)
#define W2T_OFF  (3 << 20)
#define W1T_OFF  (4 << 20)
#define WS_NEED  (12 << 20)

__device__ __forceinline__ unsigned short f2bf(float f) {
    union { float f; unsigned int u; } v; v.f = f;
    unsigned int u = v.u;
    return (unsigned short)((u + 0x7fffu + ((u >> 16) & 1u)) >> 16);
}

// ---- prep: [0,1024) W1 transpose->bf16; [1024,1040) W2T; 1040 sort ----
__global__ __launch_bounds__(256) void nk_prep(const float* __restrict__ W1,
                                               const float* __restrict__ W2,
                                               const int* __restrict__ task_id,
                                               unsigned short* __restrict__ w1t,
                                               unsigned short* __restrict__ w2t,
                                               int* __restrict__ wsi) {
    int bid = blockIdx.x;
    int tid = threadIdx.x;
    if (bid < 1024) {
        __shared__ float tile[64][65];
        int hx = bid & 7, dy = (bid >> 3) & 7, t = bid >> 6;
        int cx = tid & 63, ry = tid >> 6;
        const float* src = W1 + ((size_t)t * D_ + dy * 64) * H_ + hx * 64;
#pragma unroll
        for (int i = 0; i < 16; ++i) {
            int row = i * 4 + ry;
            tile[row][cx] = src[(size_t)row * H_ + cx];
        }
        __syncthreads();
        unsigned short* dst = w1t + ((size_t)t * H_ + hx * 64) * D_ + dy * 64;
        int c4 = tid & 15, hr0 = tid >> 4;
#pragma unroll
        for (int i = 0; i < 4; ++i) {
            int hr = hr0 + i * 16;
            unsigned short uu[4] = { f2bf(tile[c4 * 4 + 0][hr]), f2bf(tile[c4 * 4 + 1][hr]),
                                     f2bf(tile[c4 * 4 + 2][hr]), f2bf(tile[c4 * 4 + 3][hr]) };
            *(uint2*)(dst + (size_t)hr * D_ + c4 * 4) = *(const uint2*)uu;
        }
    } else if (bid < 1040) {
        // W2 [t][512][18] fp32 -> w2t [t][32][512] bf16 (a>=18 zero)
        int t = bid - 1024;
        const float* src = W2 + (size_t)t * H_ * A_;
        unsigned short* dst = w2t + (size_t)t * 32 * H_;
#pragma unroll
        for (int i = 0; i < 2; ++i) {
            int h = tid * 2 + i;
            float v[A_];
#pragma unroll
            for (int a = 0; a < A_; ++a) v[a] = src[(size_t)h * A_ + a];
#pragma unroll
            for (int a = 0; a < A_; ++a) dst[(size_t)a * H_ + h] = f2bf(v[a]);
#pragma unroll
            for (int a = A_; a < 32; ++a) dst[(size_t)a * H_ + h] = 0;
        }
    } else {
        __shared__ int cnt[T_], cur[T_], soff[T_];
        if (tid < T_) { cnt[tid] = 0; cur[tid] = 0; }
        __syncthreads();
        for (int b = tid; b < B_; b += 256) atomicAdd(&cnt[task_id[b]], 1);
        __syncthreads();
        if (tid == 0) {
            int off = 0;
            for (int t = 0; t < T_; ++t) {
                soff[t] = off; wsi[17 + t] = off;
                off += cnt[t];
            }
            wsi[17 + T_] = off;
        }
        __syncthreads();
        for (int b = tid; b < B_; b += 256) {
            int t = task_id[b];
            int pos = atomicAdd(&cur[t], 1);
            wsi[256 + soff[t] + pos] = b;
        }
    }
}

// ---- fused, XCD-pinned: c = blockIdx.x handles tasks {c, c+8} ----
__global__ __launch_bounds__(512) void nk_fused(
        const float* __restrict__ xs,
        const unsigned short* __restrict__ w1t,
        const unsigned short* __restrict__ w2t,
        const float* __restrict__ b1, const float* __restrict__ b2,
        const int* __restrict__ action, float* __restrict__ out,
        const int* __restrict__ wsi) {
    __shared__ unsigned short x_lds[16][520];   // bf16 xs tile
    __shared__ unsigned short h_lds[16][520];   // bf16 h tile
    __shared__ float lg_lds[16][34];
    __shared__ int sidx[16];

    int c = blockIdx.x;                  // XCD id (linear%8 == blockIdx.x)
    int tid = threadIdx.x, lane = tid & 63, w = tid >> 6;
    int r15 = lane & 15, kg = lane >> 4;

    int o0 = wsi[17 + c],     n0 = wsi[18 + c] - o0;      // task c
    int o1 = wsi[17 + c + 8], n1 = wsi[18 + c + 8] - o1;  // task c+8
    int nt0 = (n0 + 15) >> 4, nt1 = (n1 + 15) >> 4;
    int ntot = nt0 + nt1;

    for (int u = blockIdx.y; u < ntot; u += NSLOT) {
        int t, kt, off0, rT;
        if (u < nt0) { t = c; kt = u; off0 = o0; rT = n0; }
        else { t = c + 8; kt = u - nt0; off0 = o1; rT = n1; }
        int rowbase = off0 + kt * 16;
        int rows = rT - kt * 16; if (rows > 16) rows = 16;

        if (tid < 16) sidx[tid] = wsi[256 + rowbase + (tid < rows ? tid : rows - 1)];
        __syncthreads();

        // stage 16 xs rows fp32 -> bf16 LDS (thread: row=tid>>5, 16 cols)
        {
            int row = tid >> 5, col = (tid & 31) * 16;
            const float* src = xs + (size_t)sidx[row] * D_ + col;
            float4 v0 = *(const float4*)(src);
            float4 v1 = *(const float4*)(src + 4);
            float4 v2 = *(const float4*)(src + 8);
            float4 v3 = *(const float4*)(src + 12);
            unsigned short uu[16] = {
                f2bf(v0.x), f2bf(v0.y), f2bf(v0.z), f2bf(v0.w),
                f2bf(v1.x), f2bf(v1.y), f2bf(v1.z), f2bf(v1.w),
                f2bf(v2.x), f2bf(v2.y), f2bf(v2.z), f2bf(v2.w),
                f2bf(v3.x), f2bf(v3.y), f2bf(v3.z), f2bf(v3.w) };
            *(uint4*)&x_lds[row][col]     = *(const uint4*)&uu[0];
            *(uint4*)&x_lds[row][col + 8] = *(const uint4*)&uu[8];
        }
        __syncthreads();

        // ---- fc1: wave w covers cols w*64 .. w*64+63 (4 n-tiles), rows 0..15
        const unsigned short* bbase = w1t + (size_t)t * H_ * D_ + kg * 8;
        const unsigned short* bp0 = bbase + (size_t)(w * 64 + r15) * D_;
        const unsigned short* bp1 = bp0 + (size_t)16 * D_;
        const unsigned short* bp2 = bp0 + (size_t)32 * D_;
        const unsigned short* bp3 = bp0 + (size_t)48 * D_;

        f32x4 acc0 = {0.f,0.f,0.f,0.f}, acc1 = {0.f,0.f,0.f,0.f};
        f32x4 acc2 = {0.f,0.f,0.f,0.f}, acc3 = {0.f,0.f,0.f,0.f};
#pragma unroll
        for (int ks = 0; ks < 16; ++ks) {
            short8 af = *(const short8*)&x_lds[r15][ks * 32 + kg * 8];
            short8 b0 = *(const short8*)(bp0 + ks * 32);
            short8 b1f = *(const short8*)(bp1 + ks * 32);
            short8 b2f = *(const short8*)(bp2 + ks * 32);
            short8 b3f = *(const short8*)(bp3 + ks * 32);
            acc0 = __builtin_amdgcn_mfma_f32_16x16x32_bf16(af, b0, acc0, 0, 0, 0);
            acc1 = __builtin_amdgcn_mfma_f32_16x16x32_bf16(af, b1f, acc1, 0, 0, 0);
            acc2 = __builtin_amdgcn_mfma_f32_16x16x32_bf16(af, b2f, acc2, 0, 0, 0);
            acc3 = __builtin_amdgcn_mfma_f32_16x16x32_bf16(af, b3f, acc3, 0, 0, 0);
        }

        int colb = w * 64 + r15;
        float bv0 = b1[t * H_ + colb];
        float bv1 = b1[t * H_ + colb + 16];
        float bv2 = b1[t * H_ + colb + 32];
        float bv3 = b1[t * H_ + colb + 48];
#pragma unroll
        for (int j = 0; j < 4; ++j) {
            int row = kg * 4 + j;
            float v;
            v = acc0[j] + bv0; h_lds[row][colb]      = f2bf(v > 0.f ? v : 0.f);
            v = acc1[j] + bv1; h_lds[row][colb + 16] = f2bf(v > 0.f ? v : 0.f);
            v = acc2[j] + bv2; h_lds[row][colb + 32] = f2bf(v > 0.f ? v : 0.f);
            v = acc3[j] + bv3; h_lds[row][colb + 48] = f2bf(v > 0.f ? v : 0.f);
        }
        __syncthreads();

        // ---- fc2: waves 0,1; wave w covers a-cols w*16..w*16+15, K=512
        if (w < 2) {
            const unsigned short* wa = w2t + (size_t)t * 32 * H_
                                       + (size_t)(w * 16 + r15) * H_ + kg * 8;
            f32x4 c0 = {0.f,0.f,0.f,0.f};
#pragma unroll
            for (int ks = 0; ks < 16; ++ks) {
                short8 hf = *(const short8*)&h_lds[r15][ks * 32 + kg * 8];
                short8 w0 = *(const short8*)(wa + ks * 32);
                c0 = __builtin_amdgcn_mfma_f32_16x16x32_bf16(hf, w0, c0, 0, 0, 0);
            }
            int a = w * 16 + r15;
            float bb = (a < A_) ? b2[t * A_ + a] : 0.f;
#pragma unroll
            for (int j = 0; j < 4; ++j) {
                lg_lds[kg * 4 + j][a] = c0[j] + bb;
            }
        }
        __syncthreads();

        // ---- softmax + outputs: one thread per row
        if (tid < rows) {
            int b = sidx[tid];
            float logits[A_];
            float m = -1e30f;
#pragma unroll
            for (int a = 0; a < A_; ++a) {
                logits[a] = lg_lds[tid][a];
                m = fmaxf(m, logits[a]);
            }
            float S = 0.f, sle = 0.f;
#pragma unroll
            for (int a = 0; a < A_; ++a) {
                float e = expf(logits[a] - m);
                S += e;
                sle += logits[a] * e;
            }
            float logZ = m + logf(S);
            int as = action[b];
            out[b] = (float)as;
            out[B_ + b] = logits[as] - logZ;
            out[2 * B_ + b] = logZ - sle / S;
        }
        __syncthreads();   // protect sidx/x_lds/lg_lds before next unit
    }
}

// ---------------- fallback path (round-1, known-good) ----------------

__global__ void nk_init(int* wsi) { int i = threadIdx.x; if (i < 50) wsi[i] = 0; }

__global__ void nk_count(const int* task_id, int* wsi) {
    int b = blockIdx.x * blockDim.x + threadIdx.x;
    if (b < B_) atomicAdd(&wsi[1 + task_id[b]], 1);
}

__global__ void nk_plan(int* wsi) {
    int off = 0, tot = 0;
    for (int t = 0; t < T_; ++t) {
        wsi[17 + t] = off;
        int cnt = wsi[1 + t];
        int nt = (cnt + MTF - 1) / MTF;
        for (int k = 0; k < nt; ++k) wsi[50 + tot++] = (t << 16) | k;
        off += cnt;
    }
    wsi[17 + T_] = off;
    wsi[0] = tot;
}

__global__ void nk_scatter(const int* task_id, int* wsi) {
    int b = blockIdx.x * blockDim.x + threadIdx.x;
    if (b < B_) {
        int t = task_id[b];
        int pos = atomicAdd(&wsi[34 + t], 1);
        wsi[256 + wsi[17 + t] + pos] = b;
    }
}

__global__ __launch_bounds__(512) void nk_main(
        const float* __restrict__ xs, const float* __restrict__ W1,
        const float* __restrict__ b1, const float* __restrict__ W2,
        const float* __restrict__ b2, const int* __restrict__ task_id,
        const int* __restrict__ action, float* __restrict__ out,
        const int* __restrict__ wsi) {
    __shared__ float tile[MTF][D_];
    __shared__ int sidx[MTF];
    int bid = blockIdx.x;
    if (bid >= wsi[0]) return;
    int code = wsi[50 + bid];
    int t = code >> 16, kt = code & 0xffff;
    int off0 = wsi[17 + t], off1 = wsi[17 + t + 1];
    int base = off0 + kt * MTF;
    int rows = off1 - base; if (rows > MTF) rows = MTF;
    int tid = threadIdx.x;
    if (tid < MTF) sidx[tid] = (tid < rows) ? wsi[256 + base + tid] : -1;
    __syncthreads();
    for (int i = 0; i < MTF; ++i) {
        int b = sidx[i];
        tile[i][tid] = (b >= 0) ? xs[(size_t)b * D_ + tid] : 0.f;
    }
    __syncthreads();
    const float* w1p = W1 + (size_t)t * D_ * H_ + tid;
    float acc[MTF];
#pragma unroll
    for (int i = 0; i < MTF; ++i) acc[i] = 0.f;
    for (int d = 0; d < D_; d += 4) {
        float w0 = w1p[(size_t)(d + 0) * H_];
        float w1v = w1p[(size_t)(d + 1) * H_];
        float w2v = w1p[(size_t)(d + 2) * H_];
        float w3v = w1p[(size_t)(d + 3) * H_];
#pragma unroll
        for (int i = 0; i < MTF; ++i) {
            float4 x = *(const float4*)&tile[i][d];
            float a0 = fmaf(x.x, w0, acc[i]);
            a0 = fmaf(x.y, w1v, a0);
            a0 = fmaf(x.z, w2v, a0);
            acc[i] = fmaf(x.w, w3v, a0);
        }
    }
    __syncthreads();
    float b1v = b1[t * H_ + tid];
#pragma unroll
    for (int i = 0; i < MTF; ++i) {
        float h = acc[i] + b1v;
        tile[i][tid] = h > 0.f ? h : 0.f;
    }
    __syncthreads();
    int g = tid >> 5, l = tid & 31;
    float lg[A_];
#pragma unroll
    for (int a = 0; a < A_; ++a) lg[a] = 0.f;
    const float* w2base = W2 + (size_t)t * H_ * A_;
    for (int hh = l; hh < H_; hh += 32) {
        float hv = tile[g][hh];
        const float* wrow = w2base + (size_t)hh * A_;
#pragma unroll
        for (int a = 0; a < A_; ++a) lg[a] = fmaf(hv, wrow[a], lg[a]);
    }
#pragma unroll
    for (int a = 0; a < A_; ++a) {
        lg[a] += __shfl_down(lg[a], 16, 32);
        lg[a] += __shfl_down(lg[a], 8, 32);
        lg[a] += __shfl_down(lg[a], 4, 32);
        lg[a] += __shfl_down(lg[a], 2, 32);
        lg[a] += __shfl_down(lg[a], 1, 32);
    }
    if (l == 0 && g < rows) {
        int b = sidx[g];
        float logits[A_];
        float m = -1e30f;
#pragma unroll
        for (int a = 0; a < A_; ++a) {
            logits[a] = lg[a] + b2[t * A_ + a];
            m = fmaxf(m, logits[a]);
        }
        float S = 0.f, sle = 0.f;
#pragma unroll
        for (int a = 0; a < A_; ++a) {
            float e = expf(logits[a] - m);
            S += e;
            sle += logits[a] * e;
        }
        float logZ = m + logf(S);
        int as = action[b];
        out[b] = (float)as;
        out[B_ + b] = logits[as] - logZ;
        out[2 * B_ + b] = logZ - sle / S;
    }
}

extern "C" void kernel_launch(void* const* d_in, const int* in_sizes, int n_in,
                              void* d_out, int out_size, void* d_ws, size_t ws_size,
                              hipStream_t stream) {
    const float* xs = (const float*)d_in[0];
    const float* W1 = (const float*)d_in[1];
    const float* b1 = (const float*)d_in[2];
    const float* W2 = (const float*)d_in[3];
    const float* b2 = (const float*)d_in[4];
    const int* task_id = (const int*)d_in[5];
    const int* action = (const int*)d_in[6];
    float* out = (float*)d_out;

    if (ws_size >= WS_NEED) {
        unsigned char* wsb = (unsigned char*)d_ws;
        int* wsi = (int*)d_ws;
        unsigned short* w2t = (unsigned short*)(wsb + W2T_OFF);
        unsigned short* w1t = (unsigned short*)(wsb + W1T_OFF);

        nk_prep<<<1041, 256, 0, stream>>>(W1, W2, task_id, w1t, w2t, wsi);
        nk_fused<<<dim3(8, NSLOT), 512, 0, stream>>>(xs, w1t, w2t, b1, b2,
                                                     action, out, wsi);
    } else {
        int* wsi = (int*)d_ws;
        nk_init<<<1, 64, 0, stream>>>(wsi);
        nk_count<<<(B_ + 255) / 256, 256, 0, stream>>>(task_id, wsi);
        nk_plan<<<1, 1, 0, stream>>>(wsi);
        nk_scatter<<<(B_ + 255) / 256, 256, 0, stream>>>(task_id, wsi);
        nk_main<<<MAXTILESF, 512, 0, stream>>>(xs, W1, b1, W2, b2, task_id, action, out, wsi);
    }
}